// Round 1
// baseline (614.975 us; speedup 1.0000x reference)
//
#include <hip/hip_runtime.h>

// Instant-NGP hash-grid encoding forward.
// N points x 16 levels x 2 features. One thread per (point, level):
//   lane = level (16 lanes/point) -> float2 output store is fully coalesced
//   (one wave writes 4 points x 32 floats = 512 contiguous bytes).
//
// res table: floor(16 * b^i), b = fl32(exp((ln512 - ln16)/15)) which rounds
// UP from 2^(1/3) -> levels {3,6,9,12,15} floor to exact powers of two.
// (Fallback hypothesis if absmax ~1e-4: {31,63,127,255,511}.)
static __device__ __constant__ float c_res[16] = {
    16.f, 20.f, 25.f, 32.f, 40.f, 50.f, 64.f, 80.f,
    101.f, 128.f, 161.f, 203.f, 256.f, 322.f, 406.f, 512.f
};

#define HASH_MASK ((1u << 19) - 1u)
#define P2 2654435761u
#define P3 805459861u

__global__ __launch_bounds__(256) void hashgrid_fwd(
    const float* __restrict__ x,
    const float* __restrict__ emb,
    float* __restrict__ out,
    int npts)
{
    int tid = blockIdx.x * 256 + threadIdx.x;
    int p = tid >> 4;   // point index
    int l = tid & 15;   // level index
    if (p >= npts) return;

    // 16 lanes of the same point read the same 12 bytes -> L1 broadcast.
    float px = x[p * 3 + 0];
    float py = x[p * 3 + 1];
    float pz = x[p * 3 + 2];

    float res = c_res[l];

    // x_norm = x exactly (room is the unit cube): xs = x * res, single f32 mul.
    float xs_x = px * res, xs_y = py * res, xs_z = pz * res;
    float fx = floorf(xs_x), fy = floorf(xs_y), fz = floorf(xs_z);
    float wx1 = xs_x - fx, wy1 = xs_y - fy, wz1 = xs_z - fz;
    float wx0 = 1.0f - wx1, wy0 = 1.0f - wy1, wz0 = 1.0f - wz1;

    unsigned ux = (unsigned)fx, uy = (unsigned)fy, uz = (unsigned)fz;

    unsigned hx0 = ux;                 // prime 1
    unsigned hx1 = ux + 1u;
    unsigned hy0 = uy * P2;
    unsigned hy1 = (uy + 1u) * P2;
    unsigned hz0 = uz * P3;
    unsigned hz1 = (uz + 1u) * P3;

    // corner order: (dx,dy,dz), dz innermost (matches OFFSETS enumeration)
    unsigned h000 = (hx0 ^ hy0 ^ hz0) & HASH_MASK;
    unsigned h001 = (hx0 ^ hy0 ^ hz1) & HASH_MASK;
    unsigned h010 = (hx0 ^ hy1 ^ hz0) & HASH_MASK;
    unsigned h011 = (hx0 ^ hy1 ^ hz1) & HASH_MASK;
    unsigned h100 = (hx1 ^ hy0 ^ hz0) & HASH_MASK;
    unsigned h101 = (hx1 ^ hy0 ^ hz1) & HASH_MASK;
    unsigned h110 = (hx1 ^ hy1 ^ hz0) & HASH_MASK;
    unsigned h111 = (hx1 ^ hy1 ^ hz1) & HASH_MASK;

    const float2* e = (const float2*)emb;
    // issue all 8 gathers up front; compiler schedules them in flight together
    float2 e000 = e[h000];
    float2 e001 = e[h001];
    float2 e010 = e[h010];
    float2 e011 = e[h011];
    float2 e100 = e[h100];
    float2 e101 = e[h101];
    float2 e110 = e[h110];
    float2 e111 = e[h111];

    float wxy00 = wx0 * wy0;
    float wxy01 = wx0 * wy1;
    float wxy10 = wx1 * wy0;
    float wxy11 = wx1 * wy1;

    float c000 = wxy00 * wz0, c001 = wxy00 * wz1;
    float c010 = wxy01 * wz0, c011 = wxy01 * wz1;
    float c100 = wxy10 * wz0, c101 = wxy10 * wz1;
    float c110 = wxy11 * wz0, c111 = wxy11 * wz1;

    float f0 = c000 * e000.x;
    float f1 = c000 * e000.y;
    f0 = fmaf(c001, e001.x, f0);  f1 = fmaf(c001, e001.y, f1);
    f0 = fmaf(c010, e010.x, f0);  f1 = fmaf(c010, e010.y, f1);
    f0 = fmaf(c011, e011.x, f0);  f1 = fmaf(c011, e011.y, f1);
    f0 = fmaf(c100, e100.x, f0);  f1 = fmaf(c100, e100.y, f1);
    f0 = fmaf(c101, e101.x, f0);  f1 = fmaf(c101, e101.y, f1);
    f0 = fmaf(c110, e110.x, f0);  f1 = fmaf(c110, e110.y, f1);
    f0 = fmaf(c111, e111.x, f0);  f1 = fmaf(c111, e111.y, f1);

    float2 o;
    o.x = f0;
    o.y = f1;
    ((float2*)out)[p * 16 + l] = o;
}

extern "C" void kernel_launch(void* const* d_in, const int* in_sizes, int n_in,
                              void* d_out, int out_size, void* d_ws, size_t ws_size,
                              hipStream_t stream) {
    const float* x   = (const float*)d_in[0];
    const float* emb = (const float*)d_in[1];
    float* out = (float*)d_out;
    int npts = in_sizes[0] / 3;

    int total = npts * 16;
    int blocks = (total + 255) / 256;
    hashgrid_fwd<<<blocks, 256, 0, stream>>>(x, emb, out, npts);
}